// Round 3
// baseline (13675.568 us; speedup 1.0000x reference)
//
#include <hip/hip_runtime.h>
#include <hip/hip_bf16.h>
#include <stdint.h>

typedef unsigned short u16;
typedef unsigned int u32;
typedef __attribute__((ext_vector_type(8))) short bf16x8;
typedef __attribute__((ext_vector_type(4))) float f32x4;
typedef __attribute__((ext_vector_type(4))) u32 u32x4;

#define TT 512
#define BB 32
#define HH 512
#define WPS (2048*512)   // plane stride (u16) for W^T planes
#define RCZ 8            // Z ring capacity in 128-row tiles (4 timesteps each)
#define HR1 24           // h1 ring slots
#define HR2 8            // h2 ring slots

__device__ __forceinline__ u16 f2bf(float f) {
  u32 u = __builtin_bit_cast(u32, f);
  return (u16)((u + 0x7FFFu + ((u >> 16) & 1u)) >> 16);   // RTNE
}
__device__ __forceinline__ float bf2f(u16 h) {
  u32 u = ((u32)h) << 16;
  return __builtin_bit_cast(float, u);
}
__device__ __forceinline__ float sigm(float x) { return 1.0f / (1.0f + expf(-x)); }

__device__ __forceinline__ f32x4 mfma16(bf16x8 a, bf16x8 b, f32x4 c) {
  return __builtin_amdgcn_mfma_f32_16x16x32_bf16(a, b, c, 0, 0, 0);
}

__device__ void spin_ge(u32* p, u32 tgt, int* bail, u32* err) {
  if (*bail) return;
  int n = 0;
  while (__hip_atomic_load(p, __ATOMIC_ACQUIRE, __HIP_MEMORY_SCOPE_AGENT) < tgt) {
    __builtin_amdgcn_s_sleep(8);
    if (++n > 600000) {          // ~0.15s: set err and run free (wrong answer beats hang)
      *bail = 1;
      __hip_atomic_fetch_add(err, 1u, __ATOMIC_RELAXED, __HIP_MEMORY_SCOPE_AGENT);
      return;
    }
  }
}

// ---------- prep: exact 3-plane bf16 split of W, transposed to [plane][n=2048][k=512] ----------
__global__ void prep_w(const float* __restrict__ W,
                       u16* __restrict__ WxT, u16* __restrict__ WhT) {
  int i = blockIdx.x * 256 + threadIdx.x;
  if (i >= 2048 * 1024) return;
  int n = i >> 10, k = i & 1023;
  float v = W[(size_t)k * 2048 + n];
  u16 p0 = f2bf(v);  float r  = v - bf2f(p0);
  u16 p1 = f2bf(r);  float r2 = r - bf2f(p1);
  u16 p2 = f2bf(r2);
  size_t o = (size_t)n * 512 + (k & 511);
  u16* base = (k < 512) ? WxT : WhT;
  base[o] = p0;
  base[(size_t)WPS + o] = p1;
  base[2 * (size_t)WPS + o] = p2;
}

// ---------- recurrent role: 64 blocks/layer, each owns 8 h-cols (32 gate-cols) ----------
// Wh^T planes in LDS (96KB, swizzled). h kept as exact 3-plane bf16 ring.
template <int LAYER>
__device__ void recur_role(char* smem, int bid,
                           const float* Zr, const float* __restrict__ bias,
                           const u16* __restrict__ WhT,
                           u16* hr, int HR, u16* h2hi,
                           u32* zc, u32* z1cnt, u32* dh, u32* err) {
  u16* wl = (u16*)smem;                          // [3][32][512] swizzled = 96KB
  float* zl = (float*)(smem + 98304);            // [64][33] f32 partials
  const int tid = threadIdx.x;
  const int j0 = bid << 3;

  for (int it = 0; it < 24; ++it) {              // stage W planes -> LDS
    int id = it * 256 + tid;                     // 6144 chunks of 16B
    int p = id >> 11;
    int rem = id & 2047;
    int c = rem >> 6;
    int m = rem & 63;
    int n = ((c >> 3) << 9) + j0 + (c & 7);      // gate*512 + column
    u32x4 v = *(const u32x4*)(WhT + (size_t)p * WPS + (size_t)n * 512 + m * 8);
    int dst = ((p << 5) + c) * 1024 + ((m * 16) ^ ((c & 7) << 4));
    *(u32x4*)((char*)wl + dst) = v;
  }

  const int ln = tid & 63, wv = tid >> 6;
  const int mt = wv & 1;                         // batch 16-row tile
  const int kh = wv >> 1;                        // K half (256 each)
  const int fr = ln & 15;
  const int kg = (ln >> 4) << 3;
  const int am = (mt << 4) + fr;
  const int eb = tid >> 3, ej = tid & 7;
  float bsv[4];
#pragma unroll
  for (int g = 0; g < 4; ++g) bsv[g] = bias[(g << 9) + j0 + ej];

  const int sw = (fr & 7) << 4;
  int cb0[3], cb1[3];
#pragma unroll
  for (int p = 0; p < 3; ++p) {
    cb0[p] = ((p << 5) + fr) * 1024;
    cb1[p] = ((p << 5) + 16 + fr) * 1024;
  }

  float creg = 0.0f;
  int bail = 0;
  __syncthreads();

#pragma unroll 1
  for (int t = 0; t < TT; ++t) {
    if (tid == 0) {
      if (t) spin_ge(dh + t, 64, &bail, err);                        // h slot t ready
      spin_ge(zc + (t >> 2), 16, &bail, err);                        // Zx tile ready
      if (LAYER == 1 && t >= HR1)                                    // h1 ring slot free
        spin_ge(z1cnt + ((t - HR1) >> 2), 16, &bail, err);
    }
    __syncthreads();

    float zxv[4];
    const float* zrow = Zr + ((size_t)((t >> 2) % RCZ) * 128 + ((t & 3) << 5) + eb) * 2048
                        + j0 + ej;
#pragma unroll
    for (int g = 0; g < 4; ++g) zxv[g] = zrow[(size_t)(g << 9)];

    const u16* hb = hr + (size_t)(t % HR) * 3 * 16384 + (size_t)am * 512;
    f32x4 acc0 = {0.f, 0.f, 0.f, 0.f}, acc1 = {0.f, 0.f, 0.f, 0.f};
#pragma unroll
    for (int s = 0; s < 8; ++s) {
      int k = (kh << 8) + (s << 5) + kg;
      bf16x8 a0 = *(const bf16x8*)(hb + k);
      bf16x8 a1 = *(const bf16x8*)(hb + 16384 + k);
      bf16x8 a2 = *(const bf16x8*)(hb + 32768 + k);
      int k2 = (k << 1) ^ sw;
      bf16x8 w0 = *(const bf16x8*)((char*)wl + cb0[0] + k2);
      bf16x8 w1 = *(const bf16x8*)((char*)wl + cb0[1] + k2);
      bf16x8 w2 = *(const bf16x8*)((char*)wl + cb0[2] + k2);
      acc0 = mfma16(a0, w0, acc0);
      acc0 = mfma16(a1, w0, acc0);
      acc0 = mfma16(a2, w0, acc0);
      acc0 = mfma16(a0, w1, acc0);
      acc0 = mfma16(a1, w1, acc0);
      acc0 = mfma16(a0, w2, acc0);
      bf16x8 u0 = *(const bf16x8*)((char*)wl + cb1[0] + k2);
      bf16x8 u1 = *(const bf16x8*)((char*)wl + cb1[1] + k2);
      bf16x8 u2 = *(const bf16x8*)((char*)wl + cb1[2] + k2);
      acc1 = mfma16(a0, u0, acc1);
      acc1 = mfma16(a1, u0, acc1);
      acc1 = mfma16(a2, u0, acc1);
      acc1 = mfma16(a0, u1, acc1);
      acc1 = mfma16(a1, u1, acc1);
      acc1 = mfma16(a0, u2, acc1);
    }
    const int mrow = (mt << 4) + ((ln >> 4) << 2);
#pragma unroll
    for (int r = 0; r < 4; ++r) {
      zl[((kh << 5) + mrow + r) * 33 + fr] = acc0[r];
      zl[((kh << 5) + mrow + r) * 33 + 16 + fr] = acc1[r];
    }
    __syncthreads();

    float z4[4];
#pragma unroll
    for (int g = 0; g < 4; ++g) {
      int c = (g << 3) + ej;
      z4[g] = zxv[g] + bsv[g] + zl[eb * 33 + c] + zl[(32 + eb) * 33 + c];
    }
    float sf = sigm(z4[0]);
    float si = sigm(z4[1]);
    float tg = tanhf(z4[2]);
    float so = sigm(z4[3]);
    float hn = so * tanhf(creg);                 // tanh of OLD c (faithful to reference)
    creg = creg * sf + tg * si;
    u16 p0 = f2bf(hn);  float r1 = hn - bf2f(p0);
    u16 p1 = f2bf(r1);  float r2 = r1 - bf2f(p1);
    u16 p2 = f2bf(r2);
    size_t wb = (size_t)((t + 1) % HR) * 3 * 16384 + (size_t)eb * 512 + j0 + ej;
    hr[wb] = p0;
    hr[wb + 16384] = p1;
    hr[wb + 32768] = p2;
    if (LAYER == 2) h2hi[(size_t)(t + 1) * 16384 + (size_t)eb * 512 + j0 + ej] = p0;
    __syncthreads();
    if (tid == 0) {
      __threadfence();
      __hip_atomic_fetch_add(dh + t + 1, 1u, __ATOMIC_RELEASE, __HIP_MEMORY_SCOPE_AGENT);
    }
  }
}

// ---------- GEMM worker job: Zslot[128][2048] tile (q,nt), fp32-equivalent 3-plane ----------
template <int SRC>   // 0: A = x (fp32, split on the fly); 1: A = h1 ring planes
__device__ void gemm_job(char* smem, const float* xA, const u16* h1r,
                         const u16* __restrict__ BT, float* Zslot, int q, int nt,
                         u32* cnt) {
  u16* As0 = (u16*)smem;                         // each [128][40] u16
  u16* As1 = As0 + 5120;
  u16* As2 = As1 + 5120;
  u16* Bs0 = As2 + 5120;
  u16* Bs1 = Bs0 + 5120;
  u16* Bs2 = Bs1 + 5120;
  const int tid = threadIdx.x;
  const int rr = tid >> 1, hf = tid & 1;
  const int m = (q << 7) + rr;
  const int tt_ = m >> 5, bb_ = m & 31;
  const float* xrow = nullptr;
  const u16* hb = nullptr;
  if constexpr (SRC == 0) {
    xrow = xA + (size_t)(bb_ * 512 + tt_) * 512;                 // x [B][T][D]
  } else {
    hb = h1r + (size_t)((tt_ + 1) % HR1) * 3 * 16384 + (size_t)bb_ * 512;
  }
  const u16* brow = BT + (size_t)((nt << 7) + rr) * 512;
  const int ln = tid & 63, wv = tid >> 6;
  const int wr = wv >> 1, wc = wv & 1;
  const int fr = ln & 15;
  const int kg = (ln >> 4) << 3;
  const int lo16 = hf << 4;

  f32x4 acc[4][4];
#pragma unroll
  for (int i = 0; i < 4; ++i)
#pragma unroll
    for (int j = 0; j < 4; ++j) acc[i][j] = (f32x4){0.f, 0.f, 0.f, 0.f};

#pragma unroll 1
  for (int kc = 0; kc < 16; ++kc) {
    const int k0 = (kc << 5) + lo16;
    if constexpr (SRC == 0) {
#pragma unroll
      for (int v = 0; v < 2; ++v) {
        f32x4 f0 = *(const f32x4*)(xrow + k0 + v * 8);
        f32x4 f1 = *(const f32x4*)(xrow + k0 + v * 8 + 4);
        bf16x8 x0, x1, x2;
#pragma unroll
        for (int e = 0; e < 4; ++e) {
          u16 q0 = f2bf(f0[e]); float r = f0[e] - bf2f(q0);
          u16 q1 = f2bf(r);     float r2 = r - bf2f(q1);
          x0[e] = (short)q0; x1[e] = (short)q1; x2[e] = (short)f2bf(r2);
          u16 s0 = f2bf(f1[e]); float u1 = f1[e] - bf2f(s0);
          u16 s1 = f2bf(u1);    float u2 = u1 - bf2f(s1);
          x0[e + 4] = (short)s0; x1[e + 4] = (short)s1; x2[e + 4] = (short)f2bf(u2);
        }
        *(bf16x8*)(As0 + rr * 40 + lo16 + v * 8) = x0;
        *(bf16x8*)(As1 + rr * 40 + lo16 + v * 8) = x1;
        *(bf16x8*)(As2 + rr * 40 + lo16 + v * 8) = x2;
      }
    } else {
      *(u32x4*)(As0 + rr * 40 + lo16)     = *(const u32x4*)(hb + k0);
      *(u32x4*)(As0 + rr * 40 + lo16 + 8) = *(const u32x4*)(hb + k0 + 8);
      *(u32x4*)(As1 + rr * 40 + lo16)     = *(const u32x4*)(hb + 16384 + k0);
      *(u32x4*)(As1 + rr * 40 + lo16 + 8) = *(const u32x4*)(hb + 16384 + k0 + 8);
      *(u32x4*)(As2 + rr * 40 + lo16)     = *(const u32x4*)(hb + 32768 + k0);
      *(u32x4*)(As2 + rr * 40 + lo16 + 8) = *(const u32x4*)(hb + 32768 + k0 + 8);
    }
    *(u32x4*)(Bs0 + rr * 40 + lo16)     = *(const u32x4*)(brow + k0);
    *(u32x4*)(Bs0 + rr * 40 + lo16 + 8) = *(const u32x4*)(brow + k0 + 8);
    *(u32x4*)(Bs1 + rr * 40 + lo16)     = *(const u32x4*)(brow + (size_t)WPS + k0);
    *(u32x4*)(Bs1 + rr * 40 + lo16 + 8) = *(const u32x4*)(brow + (size_t)WPS + k0 + 8);
    *(u32x4*)(Bs2 + rr * 40 + lo16)     = *(const u32x4*)(brow + 2 * (size_t)WPS + k0);
    *(u32x4*)(Bs2 + rr * 40 + lo16 + 8) = *(const u32x4*)(brow + 2 * (size_t)WPS + k0 + 8);
    __syncthreads();

    bf16x8 A0[4], A1[4], A2[4], B0[4], B1[4], B2[4];
#pragma unroll
    for (int i = 0; i < 4; ++i) {
      int ar = (wr << 6) + (i << 4) + fr;
      A0[i] = *(const bf16x8*)(As0 + ar * 40 + kg);
      A1[i] = *(const bf16x8*)(As1 + ar * 40 + kg);
      A2[i] = *(const bf16x8*)(As2 + ar * 40 + kg);
      int br_ = (wc << 6) + (i << 4) + fr;
      B0[i] = *(const bf16x8*)(Bs0 + br_ * 40 + kg);
      B1[i] = *(const bf16x8*)(Bs1 + br_ * 40 + kg);
      B2[i] = *(const bf16x8*)(Bs2 + br_ * 40 + kg);
    }
#pragma unroll
    for (int i = 0; i < 4; ++i)
#pragma unroll
      for (int j = 0; j < 4; ++j) {
        acc[i][j] = mfma16(A0[i], B0[j], acc[i][j]);
        acc[i][j] = mfma16(A1[i], B0[j], acc[i][j]);
        acc[i][j] = mfma16(A2[i], B0[j], acc[i][j]);
        acc[i][j] = mfma16(A0[i], B1[j], acc[i][j]);
        acc[i][j] = mfma16(A1[i], B1[j], acc[i][j]);
        acc[i][j] = mfma16(A0[i], B2[j], acc[i][j]);
      }
    __syncthreads();
  }

  const int lrbase = (wr << 6) + ((ln >> 4) << 2);
  const int lcbase = (nt << 7) + (wc << 6) + fr;
#pragma unroll
  for (int i = 0; i < 4; ++i)
#pragma unroll
    for (int j = 0; j < 4; ++j)
#pragma unroll
      for (int r = 0; r < 4; ++r)
        Zslot[(size_t)(lrbase + (i << 4) + r) * 2048 + lcbase + (j << 4)] = acc[i][j][r];
  __syncthreads();
  if (tid == 0) {
    __threadfence();
    __hip_atomic_fetch_add(cnt, 1u, __ATOMIC_RELEASE, __HIP_MEMORY_SCOPE_AGENT);
  }
}

__device__ void work_role(char* smem, int w, const float* __restrict__ x,
                          const u16* __restrict__ W0xT, const u16* __restrict__ W1xT,
                          const u16* h1r, float* Z0r, float* Z1r,
                          u32* zcnt0, u32* z1cnt, u32* dh1, u32* dh2, u32* err) {
  int bail = 0;
#pragma unroll 1
  for (int r = 0; r < 16; ++r) {
    const int q = (r << 3) + (w >> 4);
    const int nt = w & 15;
    // A: Z0 tile q = x @ W0x  (ring-free gate: L1 consumed tile q-RCZ)
    if (threadIdx.x == 0 && q >= RCZ) spin_ge(dh1 + 4 * (q - RCZ) + 4, 64, &bail, err);
    __syncthreads();
    gemm_job<0>(smem, x, nullptr, W0xT, Z0r + (size_t)(q % RCZ) * 128 * 2048, q, nt,
                zcnt0 + q);
    // B: Z1 tile q = h1 @ W1x  (h1 slots ready; Z1 ring slot free)
    if (threadIdx.x == 0) {
      spin_ge(dh1 + 4 * q + 4, 64, &bail, err);
      if (q >= RCZ) spin_ge(dh2 + 4 * (q - RCZ) + 4, 64, &bail, err);
    }
    __syncthreads();
    gemm_job<1>(smem, nullptr, h1r, W1xT, Z1r + (size_t)(q % RCZ) * 128 * 2048, q, nt,
                z1cnt + q);
  }
}

// ---------- persistent pipelined kernel: 256 blocks == 256 CUs ----------
__global__ void __launch_bounds__(256, 1) mega(
    const float* __restrict__ x,
    const float* __restrict__ bias0, const float* __restrict__ bias1,
    const u16* __restrict__ W0xT, const u16* __restrict__ W0hT,
    const u16* __restrict__ W1xT, const u16* __restrict__ W1hT,
    float* Z0r, float* Z1r, u16* h1r, u16* h2r, u16* h2hi, u32* flags) {
  __shared__ char smem[106752];
  u32* zcnt0 = flags;
  u32* z1cnt = flags + 128;
  u32* dh1 = flags + 256;
  u32* dh2 = flags + 769;
  u32* err = flags + 1282;
  int blk = blockIdx.x;
  if (blk < 64) {
    recur_role<1>(smem, blk, Z0r, bias0, W0hT, h1r, HR1, nullptr, zcnt0, z1cnt, dh1, err);
  } else if (blk < 192) {
    work_role(smem, blk - 64, x, W0xT, W1xT, h1r, Z0r, Z1r, zcnt0, z1cnt, dh1, dh2, err);
  } else {
    recur_role<2>(smem, blk - 192, Z1r, bias1, W1hT, h2r, HR2, h2hi, z1cnt, nullptr, dh2,
                  err);
  }
}

// ---------- projection from bf16-hi h2 history ----------
__global__ void proj(const u16* __restrict__ y,
                     const float* __restrict__ Wr, const float* __restrict__ br,
                     float* __restrict__ out) {
  int gw = (blockIdx.x * blockDim.x + threadIdx.x) >> 6;
  int ln = threadIdx.x & 63;
  int t = gw >> 5, b = gw & 31;
  const u16* yp = y + (size_t)(t + 1) * 16384 + (size_t)b * 512 + ln * 8;
  u32x4 v = *(const u32x4*)yp;
  float p0 = 0.f, p1 = 0.f;
#pragma unroll
  for (int jj = 0; jj < 8; ++jj) {
    u16 hh = (u16)((v[jj >> 1] >> ((jj & 1) * 16)) & 0xFFFFu);
    float yv = bf2f(hh);
    int j = ln * 8 + jj;
    p0 += yv * Wr[j * 2 + 0];
    p1 += yv * Wr[j * 2 + 1];
  }
#pragma unroll
  for (int o = 32; o; o >>= 1) { p0 += __shfl_down(p0, o, 64); p1 += __shfl_down(p1, o, 64); }
  if (ln == 0) {
    out[((size_t)b * 512 + t) * 2 + 0] = p0 + br[0];
    out[((size_t)b * 512 + t) * 2 + 1] = p1 + br[1];
  }
}

// ---------- diagnostics ----------
__global__ void fail_mark(float* out, float code) {
  if (threadIdx.x == 0 && blockIdx.x == 0) out[0] = code;
}
__global__ void err_check(const u32* flags, float* out) {
  if (threadIdx.x == 0 && blockIdx.x == 0) {
    u32 e = flags[1282];
    if (e) out[0] = 1.0e6f + (float)e;
  }
}

// ---------- host ----------
extern "C" void kernel_launch(void* const* d_in, const int* in_sizes, int n_in,
                              void* d_out, int out_size, void* d_ws, size_t ws_size,
                              hipStream_t stream) {
  (void)in_sizes; (void)n_in; (void)out_size;
  const float* x  = (const float*)d_in[0];
  const float* W0 = (const float*)d_in[1];
  const float* b0 = (const float*)d_in[2];
  const float* W1 = (const float*)d_in[3];
  const float* b1 = (const float*)d_in[4];
  const float* Wr = (const float*)d_in[5];
  const float* br = (const float*)d_in[6];
  float* out = (float*)d_out;

  char* ws = (char*)d_ws;
  size_t off = 0;
  auto take = [&](size_t n) { char* p = ws + off; off = (off + n + 255) & ~(size_t)255; return p; };

  float* Z0r  = (float*)take((size_t)RCZ * 128 * 2048 * 4);   // 8 MB
  float* Z1r  = (float*)take((size_t)RCZ * 128 * 2048 * 4);   // 8 MB
  u16*   h1r  = (u16*)take((size_t)HR1 * 3 * 16384 * 2);      // 2.25 MB
  u16*   h2r  = (u16*)take((size_t)HR2 * 3 * 16384 * 2);      // 0.75 MB
  u16*   h2hi = (u16*)take((size_t)513 * 16384 * 2);          // 16.8 MB
  u16*   W0xT = (u16*)take((size_t)3 * WPS * 2);              // 6 MB x4
  u16*   W0hT = (u16*)take((size_t)3 * WPS * 2);
  u16*   W1xT = (u16*)take((size_t)3 * WPS * 2);
  u16*   W1hT = (u16*)take((size_t)3 * WPS * 2);
  u32*   flags = (u32*)take(1283 * 4);

  if (off > ws_size) {                     // visible failure: absmax ~= 2e6
    fail_mark<<<1, 1, 0, stream>>>(out, 2.0e6f);
    return;
  }

  hipMemsetAsync(flags, 0, 1283 * 4, stream);
  hipMemsetAsync(h1r, 0, 3 * 16384 * 2, stream);   // h1 slot 0 = 0 (all planes)
  hipMemsetAsync(h2r, 0, 3 * 16384 * 2, stream);   // h2 slot 0 = 0

  prep_w<<<8192, 256, 0, stream>>>(W0, W0xT, W0hT);
  prep_w<<<8192, 256, 0, stream>>>(W1, W1xT, W1hT);
  (void)hipGetLastError();
  mega<<<256, 256, 0, stream>>>(x, b0, b1, W0xT, W0hT, W1xT, W1hT,
                                Z0r, Z1r, h1r, h2r, h2hi, flags);
  if (hipGetLastError() != hipSuccess) {   // visible failure: absmax ~= 3e6
    fail_mark<<<1, 1, 0, stream>>>(out, 3.0e6f);
    return;
  }
  proj<<<4096, 256, 0, stream>>>(h2hi, Wr, br, out);
  err_check<<<1, 1, 0, stream>>>(flags, out);   // absmax ~= 1e6+n on spin timeout
}

// Round 5
// 7057.510 us; speedup vs baseline: 1.9377x; 1.9377x over previous
//
#include <hip/hip_runtime.h>
#include <hip/hip_bf16.h>
#include <stdint.h>

typedef unsigned short u16;
typedef unsigned int u32;
typedef unsigned long long u64;
typedef __attribute__((ext_vector_type(8))) short bf16x8;
typedef __attribute__((ext_vector_type(4))) float f32x4;
typedef __attribute__((ext_vector_type(4))) u32 u32x4;

#define TT 512
#define HH 512
#define WPS ((size_t)2048 * 1024)   // full-K W^T plane stride (u16 elems)
#define HR1 8                        // h1 ring slots (per pipeline)
#define HR2 4                        // h2 ring slots

// ---- coherence-point access primitives (validity carried by in-word tags) ----
#define LD4(dst, addr)  asm volatile("global_load_dword %0, %1, off sc0 sc1"   : "=v"(dst) : "v"(addr))
#define LD16(dst, addr) asm volatile("global_load_dwordx4 %0, %1, off sc0 sc1" : "=v"(dst) : "v"(addr))
#define ST4(addr, v)    asm volatile("global_store_dword %0, %1, off sc0 sc1"  :: "v"(addr), "v"(v) : "memory")
#define ST8(addr, v)    asm volatile("global_store_dwordx2 %0, %1, off sc0 sc1":: "v"(addr), "v"(v) : "memory")
#define VM0()           do { asm volatile("s_waitcnt vmcnt(0)" ::: "memory"); \
                             __builtin_amdgcn_sched_barrier(0); } while (0)

__device__ __forceinline__ u16 f2bf(float f) {
  u32 u = __builtin_bit_cast(u32, f);
  return (u16)((u + 0x7FFFu + ((u >> 16) & 1u)) >> 16);   // RTNE
}
__device__ __forceinline__ float bf2f(u16 h) {
  u32 u = ((u32)h) << 16;
  return __builtin_bit_cast(float, u);
}
__device__ __forceinline__ float sigm(float x) { return 1.0f / (1.0f + expf(-x)); }
__device__ __forceinline__ f32x4 mfma16(bf16x8 a, bf16x8 b, f32x4 c) {
  return __builtin_amdgcn_mfma_f32_16x16x32_bf16(a, b, c, 0, 0, 0);
}
__device__ __forceinline__ u32 cvtpk(float a, float b) {
  u32 r;
  asm volatile("v_cvt_pk_bf16_f32 %0, %1, %2" : "=v"(r) : "v"(a), "v"(b));
  return r;
}
__device__ __forceinline__ void mark_err(u32* err) {
  __hip_atomic_fetch_add(err, 1u, __ATOMIC_RELAXED, __HIP_MEMORY_SCOPE_AGENT);
}

// wave-wide: wait until slots[ln] >= tgt for all 64 lanes (self-lane exempt).
// lastv caches monotone flag values so satisfied waits cost zero loads.
__device__ __forceinline__ void wait_slots(const u32* slots, int ln, u32 tgt, int self,
                                           u32* lastv, int* bail, u32* err) {
  if (*bail) return;
  bool need = (ln != self) && (*lastv < tgt);
  if (__ballot(need) == 0ull) return;
  const u32* ptr = slots + ln;
  int n = 0;
  for (;;) {
    u32 v;
    LD4(v, ptr);
    VM0();
    if (v > *lastv) *lastv = v;
    need = (ln != self) && (*lastv < tgt);
    if (__ballot(need) == 0ull) return;
    __builtin_amdgcn_s_sleep(1);
    if (++n > 300000) { *bail = 1; if (ln == 0) mark_err(err); return; }
  }
}

// ---------- prep: exact 3-plane bf16 split of W, transposed to [plane][n=2048][k=1024] ----------
__global__ void prep_w(const float* __restrict__ W, u16* __restrict__ WT) {
  int i = blockIdx.x * 256 + threadIdx.x;
  if (i >= 2048 * 1024) return;
  int n = i >> 10, k = i & 1023;
  float v = W[(size_t)k * 2048 + n];
  u16 p0 = f2bf(v);  float r  = v - bf2f(p0);
  u16 p1 = f2bf(r);  float r2 = r - bf2f(p1);
  u16 p2 = f2bf(r2);
  size_t o = (size_t)n * 1024 + k;
  WT[o] = p0;
  WT[WPS + o] = p1;
  WT[2 * WPS + o] = p2;
}

// ---------- recurrent cell block: 16 batch rows, 32 gate-cols (8 h-cols), K=1024 ----------
// L1: K = [x_t (512) | h1(t-1) (512)] @ W0cat; writes h1 idx t+1.
// L2: K = [h1(t+1-producer... idx t+1) | h2(t-1... idx t)] @ W1cat; writes h2 idx t+1 + h2hi.
// h exchanged as tag-validated u64 words {p0,p1,p2,tag} at the coherence point.
template <int LAYER>
__device__ void recur(char* smem, int p, int bid,
                      const float* __restrict__ x, const float* __restrict__ bias,
                      const u16* __restrict__ WT,
                      u64* h1w, u64* h2w, u16* h2hi,
                      u32* prog1, u32* prog2, u32* err) {
  u16* wl = (u16*)smem;                          // [3][32][512] h-part W, swizzled (96KB)
  float* zl = (float*)(smem + 98304);            // [4 kh][16][33] f32 partials
  const int tid = threadIdx.x;
  const int j0 = bid << 3;

  // stage h-part of W^T (K 512..1023) for our 32 gate-cols into LDS
  for (int it = 0; it < 24; ++it) {
    int id = it * 256 + tid;                     // 6144 chunks of 16B
    int pl = id >> 11, rem = id & 2047, c = rem >> 6, m = rem & 63;
    int n = ((c >> 3) << 9) + j0 + (c & 7);
    u32x4 v = *(const u32x4*)(WT + (size_t)pl * WPS + (size_t)n * 1024 + 512 + m * 8);
    int dst = ((pl << 5) + c) * 1024 + ((m * 16) ^ ((c & 7) << 4));
    *(u32x4*)((char*)wl + dst) = v;
  }

  const int ln = tid & 63, wv = tid >> 6;        // wv = K-quarter (256 each)
  const int fr = ln & 15, kg = (ln >> 4) << 3;
  const int dbase = (wv & 1) << 8;               // d-offset within the 512 half
  const int row16 = (ln >> 4) << 2;
  // streamed-B (x/h1-part of W, K 0..511) global row bases
  const size_t nrow0 = (size_t)(((fr >> 3) << 9) + j0 + (fr & 7)) * 1024;
  const size_t nrow1 = (size_t)((((16 + fr) >> 3) << 9) + j0 + (fr & 7)) * 1024;
  // LDS-B addressing (R3-proven swizzle)
  const int sw = (fr & 7) << 4;
  int cb0[3], cb1[3];
#pragma unroll
  for (int pl = 0; pl < 3; ++pl) {
    cb0[pl] = ((pl << 5) + fr) * 1024;
    cb1[pl] = ((pl << 5) + 16 + fr) * 1024;
  }
  const int erow = tid >> 3, ej = tid & 7;       // epilogue (tid<128): row, h-col
  float bsv[4];
#pragma unroll
  for (int g = 0; g < 4; ++g) bsv[g] = bias[(g << 9) + j0 + ej];

  const float* xrow = x + ((size_t)(p * 16 + fr) * TT) * 512;  // + t*512 later
  float creg = 0.0f;
  u32 lastf = 0, lastbp = 0;
  int bail = 0, bail2 = 0;
  __syncthreads();

#pragma unroll 1
  for (int t = 0; t < TT; ++t) {
    // --- backpressure (L1 only, off critical path on an x-wave) ---
    if (LAYER == 1 && wv == 0 && t >= HR1)
      wait_slots(prog2, ln, (u32)(t - HR1 + 1), -1, &lastbp, &bail2, err);

    // --- A-fragment acquisition ---
    const bool xwave = (LAYER == 1) && (wv < 2);
    const bool skip = (wv >= 2) && (t == 0);     // h1(0)/h2(0) are zeros
    u32x4 af0[8], af1[8], af2[8];

    if (xwave) {
      // x fp32 -> exact 3-plane split via cvt_pk (rounding-mode-agnostic exactness)
      const float* xp = xrow + (size_t)t * 512 + dbase;
#pragma unroll
      for (int s = 0; s < 8; ++s) {
        f32x4 f0 = *(const f32x4*)(xp + s * 32 + kg);
        f32x4 f1 = *(const f32x4*)(xp + s * 32 + kg + 4);
#pragma unroll
        for (int j = 0; j < 4; ++j) {
          float v0 = (j < 2) ? f0[j * 2] : f1[(j - 2) * 2];
          float v1 = (j < 2) ? f0[j * 2 + 1] : f1[(j - 2) * 2 + 1];
          u32 pk0 = cvtpk(v0, v1);
          float h0 = __builtin_bit_cast(float, pk0 << 16);
          float h1 = __builtin_bit_cast(float, pk0 & 0xFFFF0000u);
          float r0 = v0 - h0, r1 = v1 - h1;
          u32 pk1 = cvtpk(r0, r1);
          float g0 = __builtin_bit_cast(float, pk1 << 16);
          float g1 = __builtin_bit_cast(float, pk1 & 0xFFFF0000u);
          u32 s0 = __builtin_bit_cast(u32, r0 - g0);
          u32 s1 = __builtin_bit_cast(u32, r1 - g1);
          af0[s][j] = pk0;
          af1[s][j] = pk1;
          af2[s][j] = (s0 >> 16) | (s1 & 0xFFFF0000u);   // truncated 3rd plane
        }
      }
    } else if (!skip) {
      // tag-validated h words
      const u64* wb;
      u32 tag;
      const u32* flagarr;
      u32 ftgt;
      int self;
      if (LAYER == 1)      { wb = h1w + ((size_t)(t & 7) * 16 + fr) * 512 + dbase;        tag = (u32)t;     flagarr = prog1; ftgt = (u32)t;     self = bid; }
      else if (wv < 2)     { wb = h1w + ((size_t)((t + 1) & 7) * 16 + fr) * 512 + dbase;  tag = (u32)t + 1; flagarr = prog1; ftgt = (u32)t + 1; self = -1;  }
      else                 { wb = h2w + ((size_t)(t & 3) * 16 + fr) * 512 + dbase;        tag = (u32)t;     flagarr = prog2; ftgt = (u32)t;     self = bid; }
      wait_slots(flagarr, ln, ftgt, self, &lastf, &bail, err);   // heuristic pre-gate
      int tries = 0;
      for (;;) {
        u32x4 hv[8][4];
#pragma unroll
        for (int s = 0; s < 8; ++s)
#pragma unroll
          for (int j = 0; j < 4; ++j) LD16(hv[s][j], wb + s * 32 + kg + 2 * j);
        VM0();
        u32 bad = 0;
#pragma unroll
        for (int s = 0; s < 8; ++s)
#pragma unroll
          for (int j = 0; j < 4; ++j) {
            u32 lo0 = hv[s][j].x, hi0 = hv[s][j].y, lo1 = hv[s][j].z, hi1 = hv[s][j].w;
            af0[s][j] = (lo0 & 0xFFFFu) | (lo1 << 16);
            af1[s][j] = (lo0 >> 16) | (hi1 & 0u) | (lo1 & 0xFFFF0000u);
            af2[s][j] = (hi0 & 0xFFFFu) | (hi1 << 16);
            bad |= (hi0 >> 16) ^ tag;
            bad |= (hi1 >> 16) ^ tag;
          }
        if (__ballot(bad != 0) == 0ull) break;
        if (++tries > 100000) { if (ln == 0) mark_err(err); break; }
        __builtin_amdgcn_s_sleep(1);
      }
    }

    // --- MFMA: 2 n-tiles x 8 k-tiles x 6 products ---
    f32x4 acc0 = {0.f, 0.f, 0.f, 0.f}, acc1 = {0.f, 0.f, 0.f, 0.f};
    if (!skip) {
      const bool streamB = (wv < 2);             // K 0..511 part streams from global/L2
#pragma unroll
      for (int s = 0; s < 8; ++s) {
        bf16x8 a0 = __builtin_bit_cast(bf16x8, af0[s]);
        bf16x8 a1 = __builtin_bit_cast(bf16x8, af1[s]);
        bf16x8 a2 = __builtin_bit_cast(bf16x8, af2[s]);
        bf16x8 w0, w1, w2, v0, v1, v2;
        if (streamB) {
          size_t k = (size_t)dbase + s * 32 + kg;
          w0 = *(const bf16x8*)(WT + nrow0 + k);
          w1 = *(const bf16x8*)(WT + WPS + nrow0 + k);
          w2 = *(const bf16x8*)(WT + 2 * WPS + nrow0 + k);
          v0 = *(const bf16x8*)(WT + nrow1 + k);
          v1 = *(const bf16x8*)(WT + WPS + nrow1 + k);
          v2 = *(const bf16x8*)(WT + 2 * WPS + nrow1 + k);
        } else {
          int k2 = ((dbase + s * 32 + kg) << 1) ^ sw;
          w0 = *(const bf16x8*)((char*)wl + cb0[0] + k2);
          w1 = *(const bf16x8*)((char*)wl + cb0[1] + k2);
          w2 = *(const bf16x8*)((char*)wl + cb0[2] + k2);
          v0 = *(const bf16x8*)((char*)wl + cb1[0] + k2);
          v1 = *(const bf16x8*)((char*)wl + cb1[1] + k2);
          v2 = *(const bf16x8*)((char*)wl + cb1[2] + k2);
        }
        acc0 = mfma16(a0, w0, acc0);
        acc0 = mfma16(a1, w0, acc0);
        acc0 = mfma16(a2, w0, acc0);
        acc0 = mfma16(a0, w1, acc0);
        acc0 = mfma16(a1, w1, acc0);
        acc0 = mfma16(a0, w2, acc0);
        acc1 = mfma16(a0, v0, acc1);
        acc1 = mfma16(a1, v0, acc1);
        acc1 = mfma16(a2, v0, acc1);
        acc1 = mfma16(a0, v1, acc1);
        acc1 = mfma16(a1, v1, acc1);
        acc1 = mfma16(a0, v2, acc1);
      }
    }
#pragma unroll
    for (int r = 0; r < 4; ++r) {
      zl[(wv * 16 + row16 + r) * 33 + fr] = acc0[r];
      zl[(wv * 16 + row16 + r) * 33 + 16 + fr] = acc1[r];
    }
    __syncthreads();

    // --- epilogue: gates + h store (tagged word) ---
    if (tid < 128) {
      float z4[4];
#pragma unroll
      for (int g = 0; g < 4; ++g) {
        int c = (g << 3) + ej;
        z4[g] = bsv[g] + zl[(erow)*33 + c] + zl[(16 + erow) * 33 + c]
                       + zl[(32 + erow) * 33 + c] + zl[(48 + erow) * 33 + c];
      }
      float sf = sigm(z4[0]);
      float si = sigm(z4[1]);
      float tg = tanhf(z4[2]);
      float so = sigm(z4[3]);
      float hn = so * tanhf(creg);               // tanh of OLD c (faithful to reference)
      creg = creg * sf + tg * si;
      u16 p0 = f2bf(hn);  float r1 = hn - bf2f(p0);
      u16 p1 = f2bf(r1);  float r2 = r1 - bf2f(p1);
      u16 p2 = f2bf(r2);
      u32 lo = (u32)p0 | ((u32)p1 << 16);
      u32 hi = (u32)p2 | ((u32)(t + 1) << 16);
      u64 word = (u64)lo | ((u64)hi << 32);
      if (LAYER == 1) {
        ST8(h1w + ((size_t)((t + 1) & 7) * 16 + erow) * 512 + j0 + ej, word);
      } else {
        ST8(h2w + ((size_t)((t + 1) & 3) * 16 + erow) * 512 + j0 + ej, word);
        h2hi[(size_t)(t + 1) * 16384 + (size_t)(p * 16 + erow) * 512 + j0 + ej] = p0;
      }
    }
    __syncthreads();
    if (tid == 0) {
      u32* po = (LAYER == 1) ? (prog1 + bid) : (prog2 + bid);
      ST4(po, (u32)(t + 1));
    }
  }
}

// ---------- persistent kernel: 2 pipelines x 2 layers x 64 blocks ----------
__global__ void __launch_bounds__(256, 1) mega(
    const float* __restrict__ x,
    const float* __restrict__ bias0, const float* __restrict__ bias1,
    const u16* __restrict__ W0T, const u16* __restrict__ W1T,
    u64* h1w_all, u64* h2w_all, u16* h2hi, u32* flags) {
  __shared__ char smem[106752];
  int blk = blockIdx.x;
  int p = blk >> 7;                     // pipeline (16 batch rows each)
  int lb = blk & 127;
  int layer = lb >> 6;
  int bid = lb & 63;
  u32* prog1 = flags + p * 128;
  u32* prog2 = prog1 + 64;
  u32* err = flags + 256;
  u64* h1w = h1w_all + (size_t)p * HR1 * 16 * 512;
  u64* h2w = h2w_all + (size_t)p * HR2 * 16 * 512;
  if (layer == 0)
    recur<1>(smem, p, bid, x, bias0, W0T, h1w, h2w, h2hi, prog1, prog2, err);
  else
    recur<2>(smem, p, bid, x, bias1, W1T, h1w, h2w, h2hi, prog1, prog2, err);
}

// ---------- projection from bf16-hi h2 history ----------
__global__ void proj(const u16* __restrict__ y,
                     const float* __restrict__ Wr, const float* __restrict__ br,
                     float* __restrict__ out) {
  int gw = (blockIdx.x * blockDim.x + threadIdx.x) >> 6;
  int ln = threadIdx.x & 63;
  int t = gw >> 5, b = gw & 31;
  const u16* yp = y + (size_t)(t + 1) * 16384 + (size_t)b * 512 + ln * 8;
  u32x4 v = *(const u32x4*)yp;
  float p0 = 0.f, p1 = 0.f;
#pragma unroll
  for (int jj = 0; jj < 8; ++jj) {
    u16 hh = (u16)((v[jj >> 1] >> ((jj & 1) * 16)) & 0xFFFFu);
    float yv = bf2f(hh);
    int j = ln * 8 + jj;
    p0 += yv * Wr[j * 2 + 0];
    p1 += yv * Wr[j * 2 + 1];
  }
#pragma unroll
  for (int o = 32; o; o >>= 1) { p0 += __shfl_down(p0, o, 64); p1 += __shfl_down(p1, o, 64); }
  if (ln == 0) {
    out[((size_t)b * 512 + t) * 2 + 0] = p0 + br[0];
    out[((size_t)b * 512 + t) * 2 + 1] = p1 + br[1];
  }
}

// ---------- diagnostics ----------
__global__ void fail_mark(float* out, float code) {
  if (threadIdx.x == 0 && blockIdx.x == 0) out[0] = code;
}
__global__ void err_check(const u32* flags, float* out) {
  if (threadIdx.x == 0 && blockIdx.x == 0) {
    u32 e = flags[256];
    if (e) out[0] = 1.0e6f + (float)e;
  }
}

// ---------- host ----------
extern "C" void kernel_launch(void* const* d_in, const int* in_sizes, int n_in,
                              void* d_out, int out_size, void* d_ws, size_t ws_size,
                              hipStream_t stream) {
  (void)in_sizes; (void)n_in; (void)out_size;
  const float* x  = (const float*)d_in[0];
  const float* W0 = (const float*)d_in[1];
  const float* b0 = (const float*)d_in[2];
  const float* W1 = (const float*)d_in[3];
  const float* b1 = (const float*)d_in[4];
  const float* Wr = (const float*)d_in[5];
  const float* br = (const float*)d_in[6];
  float* out = (float*)d_out;

  char* ws = (char*)d_ws;
  size_t off = 0;
  auto take = [&](size_t n) { char* p = ws + off; off = (off + n + 255) & ~(size_t)255; return p; };

  u16* W0T   = (u16*)take(3 * WPS * 2);                       // 12.6 MB
  u16* W1T   = (u16*)take(3 * WPS * 2);                       // 12.6 MB
  u64* h1w   = (u64*)take((size_t)2 * HR1 * 16 * 512 * 8);    // 1 MB
  u64* h2w   = (u64*)take((size_t)2 * HR2 * 16 * 512 * 8);    // 0.5 MB
  u16* h2hi  = (u16*)take((size_t)513 * 16384 * 2);           // 16.8 MB
  u32* flags = (u32*)take(257 * 4);

  if (off > ws_size) {                  // visible failure: absmax ~= 2e6
    fail_mark<<<1, 1, 0, stream>>>(out, 2.0e6f);
    return;
  }

  hipMemsetAsync(flags, 0, 257 * 4, stream);

  prep_w<<<8192, 256, 0, stream>>>(W0, W0T);
  prep_w<<<8192, 256, 0, stream>>>(W1, W1T);
  (void)hipGetLastError();
  mega<<<256, 256, 0, stream>>>(x, b0, b1, W0T, W1T, h1w, h2w, h2hi, flags);
  if (hipGetLastError() != hipSuccess) {   // visible failure: absmax ~= 3e6
    fail_mark<<<1, 1, 0, stream>>>(out, 3.0e6f);
    return;
  }
  proj<<<4096, 256, 0, stream>>>(h2hi, Wr, br, out);
  err_check<<<1, 1, 0, stream>>>(flags, out);   // absmax ~= 1e6+n on timeout
}

// Round 7
// 4046.717 us; speedup vs baseline: 3.3794x; 1.7440x over previous
//
#include <hip/hip_runtime.h>
#include <hip/hip_bf16.h>
#include <stdint.h>

typedef unsigned short u16;
typedef unsigned int u32;
typedef unsigned long long u64;
typedef __attribute__((ext_vector_type(8))) short bf16x8;
typedef __attribute__((ext_vector_type(4))) float f32x4;
typedef __attribute__((ext_vector_type(4))) u32 u32x4;

#define TT 512
#define WPS ((size_t)2048 * 1024)   // W^T plane stride (u16 elems), [n=2048][k=1024]
#define ZRS 8                       // Z ring slots
#define HRS 16                      // h1 ring slots
#define HRS2 4                      // h2 ring slots

// ---- coherence-point (L3) access primitives; ALL tagged words use these ONLY ----
#define LD16C(dst, addr) asm volatile("global_load_dwordx4 %0, %1, off sc0 sc1" : "=v"(dst) : "v"(addr))
#define LD8C(dst, addr)  asm volatile("global_load_dwordx2 %0, %1, off sc0 sc1" : "=v"(dst) : "v"(addr))
#define LD4C(dst, addr)  asm volatile("global_load_dword %0, %1, off sc0 sc1"   : "=v"(dst) : "v"(addr))
#define ST4C(addr, v)    asm volatile("global_store_dword %0, %1, off sc0 sc1"  :: "v"(addr), "v"(v) : "memory")
#define ST8C(addr, v)    asm volatile("global_store_dwordx2 %0, %1, off sc0 sc1":: "v"(addr), "v"(v) : "memory")
#define ST16C(addr, v)   asm volatile("global_store_dwordx4 %0, %1, off sc0 sc1":: "v"(addr), "v"(v) : "memory")
#define VM0()            do { asm volatile("s_waitcnt vmcnt(0)" ::: "memory"); \
                              __builtin_amdgcn_sched_barrier(0); } while (0)

__device__ __forceinline__ u16 f2bf(float f) {
  u32 u = __builtin_bit_cast(u32, f);
  return (u16)((u + 0x7FFFu + ((u >> 16) & 1u)) >> 16);   // RTNE
}
__device__ __forceinline__ float bf2f(u16 h) {
  u32 u = ((u32)h) << 16;
  return __builtin_bit_cast(float, u);
}
__device__ __forceinline__ float sigm(float x) { return 1.0f / (1.0f + expf(-x)); }
__device__ __forceinline__ f32x4 mfma16(bf16x8 a, bf16x8 b, f32x4 c) {
  return __builtin_amdgcn_mfma_f32_16x16x32_bf16(a, b, c, 0, 0, 0);
}
__device__ __forceinline__ u32 cvtpk(float a, float b) {
  u32 r;
  asm volatile("v_cvt_pk_bf16_f32 %0, %1, %2" : "=v"(r) : "v"(a), "v"(b));
  return r;
}
__device__ __forceinline__ void mark_err(u32* err) {
  __hip_atomic_fetch_add(err, 1u, __ATOMIC_RELAXED, __HIP_MEMORY_SCOPE_AGENT);
}
__device__ __forceinline__ u64 pack3(float v, u32 tag) {
  u16 p0 = f2bf(v); float r1 = v - bf2f(p0);
  u16 p1 = f2bf(r1); u16 p2 = f2bf(r1 - bf2f(p1));
  return (u64)((u32)p0 | ((u32)p1 << 16)) | ((u64)((u32)p2 | (tag << 16)) << 32);
}
__device__ __forceinline__ float zval(u64 w) {
  return bf2f((u16)(w & 0xFFFFu)) + bf2f((u16)((w >> 16) & 0xFFFFu))
       + bf2f((u16)((w >> 32) & 0xFFFFu));
}

// backpressure only (>=7-step slack): wait slots[ln&31] >= tgt; lastv caches monotone values
__device__ __forceinline__ void wait_slots(const u32* slots, int ln, u32 tgt,
                                           u32* lastv, int* bail, u32* err) {
  if (*bail) return;
  if (__ballot(*lastv < tgt) == 0ull) return;
  const u32* ptr = slots + (ln & 31);
  int n = 0;
  for (;;) {
    u32 v;
    LD4C(v, ptr);
    VM0();
    if (v > *lastv) *lastv = v;
    if (__ballot(*lastv < tgt) == 0ull) return;
    __builtin_amdgcn_s_sleep(2);
    if (++n > 400000) { *bail = 1; if (ln == 0) mark_err(err); return; }
  }
}

// head-poll: one 8B tagged word per lane until fresh (cheap readiness detection)
__device__ __forceinline__ void head_poll(const u64* p, u32 texp, u32* err) {
  int n = 0;
  for (;;) {
    u64 hw;
    LD8C(hw, p);
    VM0();
    if (__ballot((u32)(hw >> 48) != texp) == 0ull) return;
    __builtin_amdgcn_s_sleep(1);
    if (++n > 600000) { if ((threadIdx.x & 63) == 0) mark_err(err); return; }
  }
}

// ---------- prep: exact 3-plane bf16 split of W, transposed to [plane][n=2048][k=1024] ----------
__global__ void prep_w(const float* __restrict__ W, u16* __restrict__ WT) {
  int i = blockIdx.x * 256 + threadIdx.x;
  if (i >= 2048 * 1024) return;
  int n = i >> 10, k = i & 1023;
  float v = W[(size_t)k * 2048 + n];
  u16 p0 = f2bf(v);  float r  = v - bf2f(p0);
  u16 p1 = f2bf(r);  float r2 = r - bf2f(p1);
  u16 p2 = f2bf(r2);
  size_t o = (size_t)n * 1024 + k;
  WT[o] = p0;
  WT[WPS + o] = p1;
  WT[2 * WPS + o] = p2;
}

// ---------- chain block: 16 batch rows x 64 gate-cols (16 h-cols), K=512 h-part ----------
// L1: z = Z0[t] + h1(t)@W0h + b -> h1(t+1).  L2: z = Zc[t] + h2(t)@W1h + b -> h2(t+1).
template <int LAYER>
__device__ void chain(char* smem, int p, int bid,
                      const float* __restrict__ bias,
                      const u16* __restrict__ WT,
                      const u64* Zring, u64* hG,
                      const u32* progOther, u32* progSelf,
                      u16* h2hi, u32* err) {
  u16* wl = (u16*)smem;                         // [2 planes][64 rows][1024B] swizzled 128KB
  float* zl = (float*)(smem + 131072);          // [32][66] f32
  const int tid = threadIdx.x;

  // stage W h-part (k 512..1023) planes 0,1; row rho = gate*16 + hcol
#pragma unroll 1
  for (int it = 0; it < 32; ++it) {
    int id = it * 256 + tid;
    int pl = id >> 12, rem = id & 4095, rho = rem >> 6, m = rem & 63;
    int n = ((rho >> 4) << 9) + (bid << 4) + (rho & 15);
    u32x4 v = *(const u32x4*)(WT + (size_t)pl * WPS + (size_t)n * 1024 + 512 + m * 8);
    int dst = pl * 65536 + rho * 1024 + ((m << 4) ^ ((rho & 7) << 4));
    *(u32x4*)((char*)wl + dst) = v;
  }

  const int ln = tid & 63, kq = tid >> 6;       // kq = K-quarter (128 each)
  const int fr = ln & 15, kg8 = (ln >> 4) << 3;
  const int row = tid >> 4, hc = tid & 15;      // epilogue: (batch row, h-col)
  float bsv[4];
#pragma unroll
  for (int g = 0; g < 4; ++g) bsv[g] = bias[(g << 9) + (bid << 4) + hc];
  const int ka = kq * 128 + kg8;
  const u16* w2base[4];
#pragma unroll
  for (int nt = 0; nt < 4; ++nt)
    w2base[nt] = WT + 2 * WPS + (size_t)((nt << 9) + (bid << 4) + fr) * 1024 + 512 + ka;
  const int hrm = (LAYER == 1) ? (HRS - 1) : (HRS2 - 1);

  float creg = 0.0f;
  u32 lastbp = 0;
  int bail = 0;
  __syncthreads();

#pragma unroll 1
  for (int t = 0; t < TT; ++t) {
    // backpressure: h1 ring overwrite gated transitively via L2 progress (L1 only)
    if (LAYER == 1 && kq == 0 && t >= HRS - 1)
      wait_slots(progOther, ln, (u32)(t - (HRS - 1)), &lastbp, &bail, err);

    const u64* hb = hG + (size_t)(t & hrm) * (16 * 512) + (size_t)fr * 512 + ka;
    const u64* zb = Zring + (size_t)(t & (ZRS - 1)) * (16 * 2048) + (size_t)row * 2048
                  + (bid << 4) + hc;
    const u32 texp = (u32)t, zexp = (u32)(t + 1);

    head_poll(hb, texp, err);                   // readiness via data tags, no flag RT

    u32x4 hv[4][4];
    u64 zw[4];
    int tries = 0;
    for (;;) {
#pragma unroll
      for (int kt = 0; kt < 4; ++kt)
#pragma unroll
        for (int j = 0; j < 4; ++j) LD16C(hv[kt][j], hb + kt * 32 + 2 * j);
#pragma unroll
      for (int g = 0; g < 4; ++g) LD8C(zw[g], zb + ((size_t)g << 9));
      VM0();
      u32 bad = 0;
#pragma unroll
      for (int kt = 0; kt < 4; ++kt)
#pragma unroll
        for (int j = 0; j < 4; ++j)
          bad |= ((hv[kt][j].y >> 16) ^ texp) | ((hv[kt][j].w >> 16) ^ texp);
#pragma unroll
      for (int g = 0; g < 4; ++g) bad |= ((u32)(zw[g] >> 48) ^ zexp);
      if (__ballot(bad != 0) == 0ull) break;
      if (++tries > 500000) { if (ln == 0) mark_err(err); break; }
      __builtin_amdgcn_s_sleep(1);
    }

    // MFMA: 4 n-tiles (gates) x 4 k-tiles x 6 products
    f32x4 acc[4] = {{0.f,0.f,0.f,0.f},{0.f,0.f,0.f,0.f},{0.f,0.f,0.f,0.f},{0.f,0.f,0.f,0.f}};
#pragma unroll
    for (int kt = 0; kt < 4; ++kt) {
      u32 r0[4], r1[4], r2[4];
#pragma unroll
      for (int j = 0; j < 4; ++j) {
        u32 lo0 = hv[kt][j].x, hi0 = hv[kt][j].y, lo1 = hv[kt][j].z, hi1 = hv[kt][j].w;
        r0[j] = (lo0 & 0xFFFFu) | (lo1 << 16);
        r1[j] = (lo0 >> 16) | (lo1 & 0xFFFF0000u);
        r2[j] = (hi0 & 0xFFFFu) | (hi1 << 16);
      }
      bf16x8 a0 = __builtin_bit_cast(bf16x8, *(u32x4*)r0);
      bf16x8 a1 = __builtin_bit_cast(bf16x8, *(u32x4*)r1);
      bf16x8 a2 = __builtin_bit_cast(bf16x8, *(u32x4*)r2);
#pragma unroll
      for (int nt = 0; nt < 4; ++nt) {
        int rho = (nt << 4) + fr;
        int kb = ((ka + kt * 32) << 1) ^ ((rho & 7) << 4);
        bf16x8 w0 = *(const bf16x8*)((char*)wl + rho * 1024 + kb);
        bf16x8 w1 = *(const bf16x8*)((char*)wl + 65536 + rho * 1024 + kb);
        bf16x8 w2 = *(const bf16x8*)(w2base[nt] + kt * 32);
        acc[nt] = mfma16(a0, w0, acc[nt]);
        acc[nt] = mfma16(a1, w0, acc[nt]);
        acc[nt] = mfma16(a2, w0, acc[nt]);
        acc[nt] = mfma16(a0, w1, acc[nt]);
        acc[nt] = mfma16(a1, w1, acc[nt]);
        acc[nt] = mfma16(a0, w2, acc[nt]);
      }
    }
    const int r4 = (ln >> 4) << 2;
    if (kq < 2) {
#pragma unroll
      for (int nt = 0; nt < 4; ++nt)
#pragma unroll
        for (int r = 0; r < 4; ++r)
          zl[(kq * 16 + r4 + r) * 66 + (nt << 4) + fr] = acc[nt][r];
    }
    __syncthreads();
    if (kq >= 2) {
#pragma unroll
      for (int nt = 0; nt < 4; ++nt)
#pragma unroll
        for (int r = 0; r < 4; ++r)
          zl[((kq - 2) * 16 + r4 + r) * 66 + (nt << 4) + fr] += acc[nt][r];
    }
    __syncthreads();

    // epilogue: one h-value per thread; tagged word stored via single-inst asm ONLY
    float z4[4];
#pragma unroll
    for (int g = 0; g < 4; ++g)
      z4[g] = zl[row * 66 + (g << 4) + hc] + zl[(16 + row) * 66 + (g << 4) + hc]
            + zval(zw[g]) + bsv[g];
    float sf = sigm(z4[0]);
    float si = sigm(z4[1]);
    float tg = tanhf(z4[2]);
    float so = sigm(z4[3]);
    float hn = so * tanhf(creg);                // tanh of OLD c (faithful to reference)
    creg = creg * sf + tg * si;
    u64 word = pack3(hn, (u32)(t + 1));
    size_t ho = (size_t)((t + 1) & hrm) * (16 * 512) + (size_t)row * 512 + (bid << 4) + hc;
    ST8C(hG + ho, word);
    if (LAYER == 2)
      h2hi[(size_t)(t + 1) * 16384 + (size_t)(p * 16 + row) * 512 + (bid << 4) + hc] =
          (u16)(word & 0xFFFFu);
    __syncthreads();
    if (tid == 0) ST4C(progSelf + bid, (u32)(t + 1));  // read-completion flag (backpressure)
  }
}

// ---------- satellite worker: strip s (32 cols), parity q; Z0 (6 ahead) + Zc ----------
__device__ void worker(char* smem, int w, const float* __restrict__ x,
                       const u16* __restrict__ W0T, const u16* __restrict__ W1T,
                       const u64* h1G, u64* Z0R, u64* ZcR,
                       const u32* prog1, const u32* prog2, u32* err) {
  const int s = w & 63, q = w >> 6;
  u16* wl1 = (u16*)smem;                        // W1x slab [2][32][1024B] 64KB
  u16* wl0 = (u16*)(smem + 65536);              // W0x slab 64KB
  float* zl = (float*)(smem + 131072);          // [32][34]
  const int tid = threadIdx.x;

#pragma unroll 1
  for (int it = 0; it < 32; ++it) {             // stage both slabs (k<512), planes 0,1
    int id = it * 256 + tid;
    int sl = id >> 12, rem = id & 4095, pl = rem >> 11, rem2 = rem & 2047;
    int rho = rem2 >> 6, m = rem2 & 63;
    const u16* WT = sl ? W0T : W1T;
    u32x4 v = *(const u32x4*)(WT + (size_t)pl * WPS + (size_t)(32 * s + rho) * 1024 + m * 8);
    int dst = sl * 65536 + pl * 32768 + rho * 1024 + ((m << 4) ^ ((rho & 7) << 4));
    *(u32x4*)((char*)wl1 + dst) = v;
  }

  const int ln = tid & 63, kq = tid >> 6;
  const int fr = ln & 15, kg8 = (ln >> 4) << 3;
  const int row = tid >> 4, c2 = (tid & 15) * 2;
  const int ka = kq * 128 + kg8;
  u32 last1[2] = {0, 0}, last2[2] = {0, 0}, lastbp[2] = {0, 0};
  int bail = 0;
  __syncthreads();

#pragma unroll 1
  for (int k = 0;; ++k) {
    int t = 2 * k + q;
    if (t > 511) break;

    // ---- Z0 jobs: x @ W0x (k<3 double-issue builds the 6-step lead) ----
    int nz = (k < 3) ? 2 : 1;
#pragma unroll 1
    for (int e = 0; e < nz; ++e) {
      int tz = (e == 0 && k < 3) ? t : t + 6;
      if (tz > 511) continue;
#pragma unroll 1
      for (int p = 0; p < 2; ++p) {
        if (kq == 0 && tz >= ZRS)
          wait_slots(prog1 + p * 32, ln, (u32)(tz - ZRS + 1), &lastbp[p], &bail, err);
        const float* xb = x + (size_t)(p * 16 + fr) * TT * 512 + (size_t)tz * 512 + ka;
        f32x4 acc[2] = {{0.f,0.f,0.f,0.f},{0.f,0.f,0.f,0.f}};
#pragma unroll
        for (int kt = 0; kt < 4; ++kt) {
          f32x4 f0 = *(const f32x4*)(xb + kt * 32);
          f32x4 f1 = *(const f32x4*)(xb + kt * 32 + 4);
          u32 r0[4], r1[4], r2[4];
#pragma unroll
          for (int j = 0; j < 4; ++j) {
            float v0 = (j < 2) ? f0[j * 2] : f1[(j - 2) * 2];
            float v1 = (j < 2) ? f0[j * 2 + 1] : f1[(j - 2) * 2 + 1];
            u32 pk0 = cvtpk(v0, v1);
            float h0 = __builtin_bit_cast(float, pk0 << 16);
            float h1f = __builtin_bit_cast(float, pk0 & 0xFFFF0000u);
            float q0 = v0 - h0, q1 = v1 - h1f;
            u32 pk1 = cvtpk(q0, q1);
            float g0 = __builtin_bit_cast(float, pk1 << 16);
            float g1 = __builtin_bit_cast(float, pk1 & 0xFFFF0000u);
            u32 s0 = __builtin_bit_cast(u32, q0 - g0);
            u32 s1 = __builtin_bit_cast(u32, q1 - g1);
            r0[j] = pk0; r1[j] = pk1;
            r2[j] = (s0 >> 16) | (s1 & 0xFFFF0000u);
          }
          bf16x8 a0 = __builtin_bit_cast(bf16x8, *(u32x4*)r0);
          bf16x8 a1 = __builtin_bit_cast(bf16x8, *(u32x4*)r1);
          bf16x8 a2 = __builtin_bit_cast(bf16x8, *(u32x4*)r2);
#pragma unroll
          for (int nt = 0; nt < 2; ++nt) {
            int rho = (nt << 4) + fr;
            int kb = ((ka + kt * 32) << 1) ^ ((rho & 7) << 4);
            bf16x8 w0 = *(const bf16x8*)((char*)wl0 + rho * 1024 + kb);
            bf16x8 w1 = *(const bf16x8*)((char*)wl0 + 32768 + rho * 1024 + kb);
            bf16x8 w2 = *(const bf16x8*)(W0T + 2 * WPS + (size_t)(32 * s + rho) * 1024 + ka + kt * 32);
            acc[nt] = mfma16(a0, w0, acc[nt]);
            acc[nt] = mfma16(a1, w0, acc[nt]);
            acc[nt] = mfma16(a2, w0, acc[nt]);
            acc[nt] = mfma16(a0, w1, acc[nt]);
            acc[nt] = mfma16(a1, w1, acc[nt]);
            acc[nt] = mfma16(a0, w2, acc[nt]);
          }
        }
        const int r4 = (ln >> 4) << 2;
        if (kq < 2) {
#pragma unroll
          for (int nt = 0; nt < 2; ++nt)
#pragma unroll
            for (int r = 0; r < 4; ++r)
              zl[(kq * 16 + r4 + r) * 34 + (nt << 4) + fr] = acc[nt][r];
        }
        __syncthreads();
        if (kq >= 2) {
#pragma unroll
          for (int nt = 0; nt < 2; ++nt)
#pragma unroll
            for (int r = 0; r < 4; ++r)
              zl[((kq - 2) * 16 + r4 + r) * 34 + (nt << 4) + fr] += acc[nt][r];
        }
        __syncthreads();
        float v0 = zl[row * 34 + c2] + zl[(16 + row) * 34 + c2];
        float v1 = zl[row * 34 + c2 + 1] + zl[(16 + row) * 34 + c2 + 1];
        u64 w0 = pack3(v0, (u32)(tz + 1));
        u64 w1 = pack3(v1, (u32)(tz + 1));
        u32x4 st = { (u32)w0, (u32)(w0 >> 32), (u32)w1, (u32)(w1 >> 32) };
        u64* dst = Z0R + (size_t)p * ZRS * 16 * 2048 + (size_t)(tz & (ZRS - 1)) * (16 * 2048)
                 + (size_t)row * 2048 + 32 * s + c2;
        ST16C(dst, st);
        __syncthreads();
      }
    }

    // ---- Zc jobs: h1(t+1) @ W1x (readiness via h tags; flags only for ring space) ----
#pragma unroll 1
    for (int p = 0; p < 2; ++p) {
      if (kq == 0 && t >= ZRS)
        wait_slots(prog2 + p * 32, ln, (u32)(t - ZRS + 1), &last2[p], &bail, err);
      const u64* hb = h1G + (size_t)p * HRS * 16 * 512
                    + (size_t)((t + 1) & (HRS - 1)) * (16 * 512) + (size_t)fr * 512 + ka;
      const u32 texp = (u32)(t + 1);
      head_poll(hb, texp, err);
      u32x4 hv[4][4];
      int tries = 0;
      for (;;) {
#pragma unroll
        for (int kt = 0; kt < 4; ++kt)
#pragma unroll
          for (int j = 0; j < 4; ++j) LD16C(hv[kt][j], hb + kt * 32 + 2 * j);
        VM0();
        u32 bad = 0;
#pragma unroll
        for (int kt = 0; kt < 4; ++kt)
#pragma unroll
          for (int j = 0; j < 4; ++j)
            bad |= ((hv[kt][j].y >> 16) ^ texp) | ((hv[kt][j].w >> 16) ^ texp);
        if (__ballot(bad != 0) == 0ull) break;
        if (++tries > 500000) { if (ln == 0) mark_err(err); break; }
        __builtin_amdgcn_s_sleep(1);
      }
      f32x4 acc[2] = {{0.f,0.f,0.f,0.f},{0.f,0.f,0.f,0.f}};
#pragma unroll
      for (int kt = 0; kt < 4; ++kt) {
        u32 r0[4], r1[4], r2[4];
#pragma unroll
        for (int j = 0; j < 4; ++j) {
          u32 lo0 = hv[kt][j].x, hi0 = hv[kt][j].y, lo1 = hv[kt][j].z, hi1 = hv[kt][j].w;
          r0[j] = (lo0 & 0xFFFFu) | (lo1 << 16);
          r1[j] = (lo0 >> 16) | (lo1 & 0xFFFF0000u);
          r2[j] = (hi0 & 0xFFFFu) | (hi1 << 16);
        }
        bf16x8 a0 = __builtin_bit_cast(bf16x8, *(u32x4*)r0);
        bf16x8 a1 = __builtin_bit_cast(bf16x8, *(u32x4*)r1);
        bf16x8 a2 = __builtin_bit_cast(bf16x8, *(u32x4*)r2);
#pragma unroll
        for (int nt = 0; nt < 2; ++nt) {
          int rho = (nt << 4) + fr;
          int kb = ((ka + kt * 32) << 1) ^ ((rho & 7) << 4);
          bf16x8 w0 = *(const bf16x8*)((char*)wl1 + rho * 1024 + kb);
          bf16x8 w1 = *(const bf16x8*)((char*)wl1 + 32768 + rho * 1024 + kb);
          bf16x8 w2 = *(const bf16x8*)(W1T + 2 * WPS + (size_t)(32 * s + rho) * 1024 + ka + kt * 32);
          acc[nt] = mfma16(a0, w0, acc[nt]);
          acc[nt] = mfma16(a1, w0, acc[nt]);
          acc[nt] = mfma16(a2, w0, acc[nt]);
          acc[nt] = mfma16(a0, w1, acc[nt]);
          acc[nt] = mfma16(a1, w1, acc[nt]);
          acc[nt] = mfma16(a0, w2, acc[nt]);
        }
      }
      const int r4 = (ln >> 4) << 2;
      if (kq < 2) {
#pragma unroll
        for (int nt = 0; nt < 2; ++nt)
#pragma unroll
          for (int r = 0; r < 4; ++r)
            zl[(kq * 16 + r4 + r) * 34 + (nt << 4) + fr] = acc[nt][r];
      }
      __syncthreads();
      if (kq >= 2) {
#pragma unroll
        for (int nt = 0; nt < 2; ++nt)
#pragma unroll
          for (int r = 0; r < 4; ++r)
            zl[((kq - 2) * 16 + r4 + r) * 34 + (nt << 4) + fr] += acc[nt][r];
      }
      __syncthreads();
      float v0 = zl[row * 34 + c2] + zl[(16 + row) * 34 + c2];
      float v1 = zl[row * 34 + c2 + 1] + zl[(16 + row) * 34 + c2 + 1];
      u64 w0 = pack3(v0, (u32)(t + 1));
      u64 w1 = pack3(v1, (u32)(t + 1));
      u32x4 st = { (u32)w0, (u32)(w0 >> 32), (u32)w1, (u32)(w1 >> 32) };
      u64* dst = ZcR + (size_t)p * ZRS * 16 * 2048 + (size_t)(t & (ZRS - 1)) * (16 * 2048)
               + (size_t)row * 2048 + 32 * s + c2;
      ST16C(dst, st);
      __syncthreads();
    }
  }
}

// ---------- persistent kernel: 256 blocks; 128 chain (2 pipes x 2 layers x 32) + 128 workers ----------
__global__ void __launch_bounds__(256, 1) mega(
    const float* __restrict__ x,
    const float* __restrict__ bias0, const float* __restrict__ bias1,
    const u16* __restrict__ W0T, const u16* __restrict__ W1T,
    u64* Z0R, u64* ZcR, u64* h1G, u64* h2G, u16* h2hi, u32* flags) {
  __shared__ char smem[139520];
  const int blk = blockIdx.x;
  const int r8 = blk & 7, g8 = blk >> 3;
  u32* prog1 = flags;          // [2][32]
  u32* prog2 = flags + 64;     // [2][32]
  u32* err = flags + 128;
  if (r8 < 2) {
    int p = r8;
    chain<1>(smem, p, g8, bias0, W0T,
             Z0R + (size_t)p * ZRS * 16 * 2048, h1G + (size_t)p * HRS * 16 * 512,
             prog2 + p * 32, prog1 + p * 32, nullptr, err);
  } else if (r8 < 4) {
    int p = r8 - 2;
    chain<2>(smem, p, g8, bias1, W1T,
             ZcR + (size_t)p * ZRS * 16 * 2048, h2G + (size_t)p * HRS2 * 16 * 512,
             nullptr, prog2 + p * 32, h2hi, err);
  } else {
    worker(smem, (r8 - 4) * 32 + g8, x, W0T, W1T, h1G, Z0R, ZcR, prog1, prog2, err);
  }
}

// ---------- projection from bf16-hi h2 history ----------
__global__ void proj(const u16* __restrict__ y,
                     const float* __restrict__ Wr, const float* __restrict__ br,
                     float* __restrict__ out) {
  int gw = (blockIdx.x * blockDim.x + threadIdx.x) >> 6;
  int ln = threadIdx.x & 63;
  int t = gw >> 5, b = gw & 31;
  const u16* yp = y + (size_t)(t + 1) * 16384 + (size_t)b * 512 + ln * 8;
  u32x4 v = *(const u32x4*)yp;
  float p0 = 0.f, p1 = 0.f;
#pragma unroll
  for (int jj = 0; jj < 8; ++jj) {
    u16 hh = (u16)((v[jj >> 1] >> ((jj & 1) * 16)) & 0xFFFFu);
    float yv = bf2f(hh);
    int j = ln * 8 + jj;
    p0 += yv * Wr[j * 2 + 0];
    p1 += yv * Wr[j * 2 + 1];
  }
#pragma unroll
  for (int o = 32; o; o >>= 1) { p0 += __shfl_down(p0, o, 64); p1 += __shfl_down(p1, o, 64); }
  if (ln == 0) {
    out[((size_t)b * 512 + t) * 2 + 0] = p0 + br[0];
    out[((size_t)b * 512 + t) * 2 + 1] = p1 + br[1];
  }
}

// ---------- diagnostics ----------
__global__ void fail_mark(float* out, float code) {
  if (threadIdx.x == 0 && blockIdx.x == 0) out[0] = code;
}
__global__ void err_check(const u32* flags, float* out) {
  if (threadIdx.x == 0 && blockIdx.x == 0) {
    u32 e = flags[128];
    if (e) out[0] = 1.0e6f + (float)e;
  }
}

// ---------- host ----------
extern "C" void kernel_launch(void* const* d_in, const int* in_sizes, int n_in,
                              void* d_out, int out_size, void* d_ws, size_t ws_size,
                              hipStream_t stream) {
  (void)in_sizes; (void)n_in; (void)out_size;
  const float* x  = (const float*)d_in[0];
  const float* W0 = (const float*)d_in[1];
  const float* b0 = (const float*)d_in[2];
  const float* W1 = (const float*)d_in[3];
  const float* b1 = (const float*)d_in[4];
  const float* Wr = (const float*)d_in[5];
  const float* br = (const float*)d_in[6];
  float* out = (float*)d_out;

  char* ws = (char*)d_ws;
  size_t off = 0;
  auto take = [&](size_t n) { char* p = ws + off; off = (off + n + 255) & ~(size_t)255; return p; };

  u16* W0T  = (u16*)take(3 * WPS * 2);                          // 12.6 MB
  u16* W1T  = (u16*)take(3 * WPS * 2);                          // 12.6 MB
  u64* Z0R  = (u64*)take((size_t)2 * ZRS * 16 * 2048 * 8);      // 4.2 MB
  u64* ZcR  = (u64*)take((size_t)2 * ZRS * 16 * 2048 * 8);      // 4.2 MB
  u64* h1G  = (u64*)take((size_t)2 * HRS * 16 * 512 * 8);       // 2.1 MB
  u64* h2G  = (u64*)take((size_t)2 * HRS2 * 16 * 512 * 8);      // 0.52 MB
  u16* h2hi = (u16*)take((size_t)513 * 16384 * 2);              // 16.8 MB
  u32* flags = (u32*)take(129 * 4);                             // total ~53 MB

  if (off > ws_size) {                   // visible failure: absmax ~= 2e6
    fail_mark<<<1, 1, 0, stream>>>(out, 2.0e6f);
    return;
  }

  hipMemsetAsync(flags, 0, 129 * 4, stream);
  // zero ALL rings: h(0)=0 with tag 0, and no garbage word can alias a future tag
  hipMemsetAsync(Z0R, 0, (size_t)2 * ZRS * 16 * 2048 * 8, stream);
  hipMemsetAsync(ZcR, 0, (size_t)2 * ZRS * 16 * 2048 * 8, stream);
  hipMemsetAsync(h1G, 0, (size_t)2 * HRS * 16 * 512 * 8, stream);
  hipMemsetAsync(h2G, 0, (size_t)2 * HRS2 * 16 * 512 * 8, stream);

  prep_w<<<8192, 256, 0, stream>>>(W0, W0T);
  prep_w<<<8192, 256, 0, stream>>>(W1, W1T);
  (void)hipGetLastError();
  mega<<<256, 256, 0, stream>>>(x, b0, b1, W0T, W1T, Z0R, ZcR, h1G, h2G, h2hi, flags);
  if (hipGetLastError() != hipSuccess) {  // visible failure: absmax ~= 3e6
    fail_mark<<<1, 1, 0, stream>>>(out, 3.0e6f);
    return;
  }
  proj<<<4096, 256, 0, stream>>>(h2hi, Wr, br, out);
  err_check<<<1, 1, 0, stream>>>(flags, out);   // absmax ~= 1e6+n on timeout
}